// Round 1
// 2552.104 us; speedup vs baseline: 1.0553x; 1.0553x over previous
//
#include <hip/hip_runtime.h>

typedef unsigned short u16;
typedef __attribute__((ext_vector_type(8))) short short8;
typedef __attribute__((ext_vector_type(4))) float f32x4;

// ---------- helpers ----------
__device__ __forceinline__ u16 f2bf(float x) {
    unsigned u = __float_as_uint(x);
    u = (u + 0x7FFFu + ((u >> 16) & 1u)) >> 16;
    return (u16)u;
}

__device__ __forceinline__ void gload16(const void* g, void* l) {
    __builtin_amdgcn_global_load_lds((const __attribute__((address_space(1))) void*)g,
                                     (__attribute__((address_space(3))) void*)l, 16, 0, 0);
}

// ---------- fp32 -> bf16 convert ----------
__global__ __launch_bounds__(256) void cvt_bf16_k(const float* __restrict__ in,
                                                  u16* __restrict__ out, int n4) {
    int i = blockIdx.x * 256 + threadIdx.x;
    if (i >= n4) return;
    float4 v = ((const float4*)in)[i];
    ushort4 o;
    o.x = f2bf(v.x); o.y = f2bf(v.y); o.z = f2bf(v.z); o.w = f2bf(v.w);
    ((ushort4*)out)[i] = o;
}

// ---------- Whh [4096][1024] -> wpack [512][1024][8] ----------
// wpack[p][k][g] = Whh[(g>>1)*1024 + p*2 + (g&1)][k]
// i.e. block p of lstm_step owns j rows {p*2, p*2+1}; col g = q*2+jj.
__global__ __launch_bounds__(256) void pack_whh(const float* __restrict__ Whh,
                                                float* __restrict__ wpack) {
    __shared__ float tile[8][260];
    const int p = blockIdx.x;       // 0..511
    const int k0 = blockIdx.y * 256; // 4 k-chunks
#pragma unroll
    for (int g = 0; g < 8; ++g) {
        int n = (g >> 1) * 1024 + p * 2 + (g & 1);
        tile[g][threadIdx.x] = Whh[(size_t)n * 1024 + k0 + threadIdx.x];
    }
    __syncthreads();
#pragma unroll
    for (int i = 0; i < 8; ++i) {
        int f = i * 256 + threadIdx.x;  // 0..2047
        int kk = f >> 3, g = f & 7;
        wpack[(size_t)p * 8192 + (size_t)(k0 + kk) * 8 + g] = tile[g][kk];
    }
}

// ---------- embedding + relu -> bf16 A-matrix rows m = t*64+b ----------
__global__ __launch_bounds__(256) void embed_relu(const int* __restrict__ tgt,
                                                  const float* __restrict__ emb,
                                                  u16* __restrict__ x_bf) {
    int t = blockIdx.x, b = blockIdx.y;
    int tok = (t == 0) ? 0 : tgt[b * 60 + t - 1];
    const float4* src = (const float4*)(emb + (size_t)tok * 1024);
    ushort4* dst = (ushort4*)(x_bf + (size_t)(t * 64 + b) * 1024);
    float4 v = src[threadIdx.x];
    ushort4 o;
    o.x = f2bf(fmaxf(v.x, 0.f)); o.y = f2bf(fmaxf(v.y, 0.f));
    o.z = f2bf(fmaxf(v.z, 0.f)); o.w = f2bf(fmaxf(v.w, 0.f));
    dst[threadIdx.x] = o;
}

// ---------- h0/c0 [b][j] -> transposed state [j][b] ----------
__global__ __launch_bounds__(256) void init_hc(const float* __restrict__ h0,
                                               const float* __restrict__ c0,
                                               float* __restrict__ hT, float* __restrict__ cT) {
    int i = blockIdx.x * 256 + threadIdx.x;  // 65536, b fast
    int j = i >> 6, b = i & 63;
    hT[i] = h0[b * 1024 + j];
    cT[i] = c0[b * 1024 + j];
}

// ---------- bf16 MFMA GEMM, A[M,K] @ B^T[N,K], K=1024, 128x128 tiles ----------
// EPI=0: out = xWT[t][n][b] (+b_ih+b_hh);  EPI=1: out = logits[b][t][v] (+b_out)
// GW: supertile width in N-tiles (group = GW x 30 blocks) for L3 locality.
template <int EPI, int GW>
__global__ __launch_bounds__(256) void gemm_bt(const u16* __restrict__ A,
                                               const u16* __restrict__ Bm,
                                               const float* __restrict__ bias0,
                                               const float* __restrict__ bias1,
                                               float* __restrict__ out) {
    constexpr int K = 1024;
    __shared__ u16 lds_a[128 * 32];
    __shared__ u16 lds_b[128 * 32];
    const int tid = threadIdx.x;
    const int lane = tid & 63, wave = tid >> 6;
    // supertile remap: groups of GW*30 blocks cover a GW-wide N-panel x all M
    const int lin = blockIdx.y * gridDim.x + blockIdx.x;
    constexpr int GSZ = GW * 30;
    const int grp = lin / GSZ, rr = lin % GSZ;
    const int tileN = (grp * GW + rr % GW) * 128;
    const int tileM = (rr / GW) * 128;
    const int wm = (wave >> 1) * 64, wn = (wave & 1) * 64;

    const int sRow = wave * 32 + (lane >> 2);
    const int sCol = (lane & 3) * 8;
    const u16* gA = A + (size_t)(tileM + sRow) * K + sCol;
    const u16* gB = Bm + (size_t)(tileN + sRow) * K + sCol;
    u16* lA = lds_a + sRow * 32 + sCol;
    u16* lB = lds_b + sRow * 32 + sCol;

    f32x4 acc[4][4] = {};
    const int fr = lane & 15, fq = lane >> 4;

    for (int k0 = 0; k0 < K; k0 += 32) {
        gload16(gA + k0, lA);
        gload16(gA + k0 + 16 * K, lA + 16 * 32);
        gload16(gB + k0, lB);
        gload16(gB + k0 + 16 * K, lB + 16 * 32);
        __syncthreads();
        short8 af[4], bfv[4];
#pragma unroll
        for (int i = 0; i < 4; ++i)
            af[i] = *(const short8*)&lds_a[(wm + i * 16 + fr) * 32 + fq * 8];
#pragma unroll
        for (int j = 0; j < 4; ++j)
            bfv[j] = *(const short8*)&lds_b[(wn + j * 16 + fr) * 32 + fq * 8];
#pragma unroll
        for (int i = 0; i < 4; ++i)
#pragma unroll
            for (int j = 0; j < 4; ++j)
                acc[i][j] = __builtin_amdgcn_mfma_f32_16x16x32_bf16(af[i], bfv[j], acc[i][j], 0, 0, 0);
        __syncthreads();
    }
    const int cr = fq * 4, cc = fr;
#pragma unroll
    for (int i = 0; i < 4; ++i) {
#pragma unroll
        for (int j = 0; j < 4; ++j) {
            int col = tileN + wn + j * 16 + cc;
            float bb;
            if (EPI == 0) bb = bias0[col] + bias1[col];
            else          bb = bias0[col];
#pragma unroll
            for (int r = 0; r < 4; ++r) {
                int row = tileM + wm + i * 16 + cr + r;  // row = t*64 + b
                float v = acc[i][j][r] + bb;
                if (EPI == 0) {
                    out[((size_t)(row >> 6) * 4096 + col) * 64 + (row & 63)] = v;
                } else {
                    out[((size_t)(row & 63) * 60 + (row >> 6)) * 32000 + col] = v;
                }
            }
        }
    }
}

// ---------- fused recurrent step: gates GEMM (full K) + LSTM update ----------
// grid 512 blocks x 128 threads. Block p owns j rows {2p, 2p+1}; its 8 gate
// columns n = q*1024 + 2p + jj live pre-packed in wpack[p] (32KB, L2-hot).
// h is read from hR (whole vector, LDS-staged) and written to hW (ping-pong:
// in-place write would race with blocks still reading h).
__global__ __launch_bounds__(128) void lstm_step(const float* __restrict__ xWT,
                                                 const float* __restrict__ wpack,
                                                 const float* __restrict__ hR,
                                                 float* __restrict__ hW,
                                                 float* __restrict__ cT,
                                                 u16* __restrict__ hs_bf, int t) {
    __shared__ __attribute__((aligned(16))) float sW[8192];     // 32KB: [k][8]
    __shared__ __attribute__((aligned(16))) float sH[2][4096];  // 2x16KB: 64k x 64b
    const int tid = threadIdx.x;
    const int p = blockIdx.x;

    // epilogue role: (jj, b); prefetch xW gates + c_old early (hide HBM latency)
    const int eb = tid & 63, ejj = tid >> 6;
    const int j = p * 2 + ejj;
    float xw[4];
    {
        const float* xbase = xWT + (size_t)t * 262144 + (size_t)j * 64 + eb;
#pragma unroll
        for (int q = 0; q < 4; ++q) xw[q] = xbase[(size_t)q * 65536];
    }
    float cold = cT[j * 64 + eb];

    // stage W panel (32KB) + h chunk 0 (16KB) via global_load_lds
    const float* wsrc = wpack + (size_t)p * 8192;
#pragma unroll
    for (int i = 0; i < 16; ++i)
        gload16(wsrc + i * 512 + tid * 4, sW + i * 512 + tid * 4);
#pragma unroll
    for (int i = 0; i < 8; ++i)
        gload16(hR + i * 512 + tid * 4, sH[0] + i * 512 + tid * 4);
    __syncthreads();

    // compute role: (g = gate col 0..7, bq = b quad); acc over K=1024
    const int g = tid >> 4, bq = (tid & 15) * 4;
    float a0 = 0.f, a1 = 0.f, a2 = 0.f, a3 = 0.f;
    for (int c = 0; c < 16; ++c) {
        if (c < 15) {  // prefetch next 64-k chunk of h into other buffer
            const float* src = hR + (c + 1) * 4096;
            float* dst = sH[(c + 1) & 1];
#pragma unroll
            for (int i = 0; i < 8; ++i)
                gload16(src + i * 512 + tid * 4, dst + i * 512 + tid * 4);
        }
        const float* hb = sH[c & 1];
        const float* wb = sW + c * 512;
#pragma unroll
        for (int kk = 0; kk < 64; ++kk) {
            f32x4 hv = *(const f32x4*)(hb + kk * 64 + bq);
            float wv = wb[kk * 8 + g];
            a0 = fmaf(hv.x, wv, a0);
            a1 = fmaf(hv.y, wv, a1);
            a2 = fmaf(hv.z, wv, a2);
            a3 = fmaf(hv.w, wv, a3);
        }
        __syncthreads();
    }

    // gather gates across threads via LDS, then update state
    float* gbuf = sH[0];
    *(f32x4*)(gbuf + g * 64 + bq) = (f32x4){a0, a1, a2, a3};
    __syncthreads();
    float gq[4];
#pragma unroll
    for (int q = 0; q < 4; ++q) gq[q] = gbuf[(q * 2 + ejj) * 64 + eb] + xw[q];
    float ig = 1.f / (1.f + __expf(-gq[0]));
    float fg = 1.f / (1.f + __expf(-gq[1]));
    float gg = tanhf(gq[2]);
    float og = 1.f / (1.f + __expf(-gq[3]));
    float cn = fg * cold + ig * gg;
    float hn = og * tanhf(cn);
    cT[j * 64 + eb] = cn;
    hW[j * 64 + eb] = hn;
    hs_bf[(size_t)(t * 64 + eb) * 1024 + j] = f2bf(hn);
}

// ---------- fused log_softmax: row in registers, one read + one write ----------
__global__ __launch_bounds__(256) void softmax_fused(float* __restrict__ logits) {
    const int tid = threadIdx.x;
    float* x = logits + (size_t)blockIdx.x * 32000;
    float4* x4 = (float4*)x;
    float4 v[31];
#pragma unroll
    for (int i = 0; i < 31; ++i) v[i] = x4[i * 256 + tid];
    float vt = x[31744 + tid];
    float m = vt;
#pragma unroll
    for (int i = 0; i < 31; ++i)
        m = fmaxf(m, fmaxf(fmaxf(v[i].x, v[i].y), fmaxf(v[i].z, v[i].w)));
#pragma unroll
    for (int o = 32; o > 0; o >>= 1) m = fmaxf(m, __shfl_xor(m, o));
    __shared__ float red[8];
    const int lane = tid & 63, wv = tid >> 6;
    if (lane == 0) red[wv] = m;
    __syncthreads();
    m = fmaxf(fmaxf(red[0], red[1]), fmaxf(red[2], red[3]));
    float s = __expf(vt - m);
#pragma unroll
    for (int i = 0; i < 31; ++i)
        s += __expf(v[i].x - m) + __expf(v[i].y - m) + __expf(v[i].z - m) + __expf(v[i].w - m);
#pragma unroll
    for (int o = 32; o > 0; o >>= 1) s += __shfl_xor(s, o);
    if (lane == 0) red[4 + wv] = s;
    __syncthreads();
    float d = m + __logf(red[4] + red[5] + red[6] + red[7]);
#pragma unroll
    for (int i = 0; i < 31; ++i) {
        v[i].x -= d; v[i].y -= d; v[i].z -= d; v[i].w -= d;
        x4[i * 256 + tid] = v[i];
    }
    x[31744 + tid] = vt - d;
}

// ---------- final h,c -> d_out tail ----------
__global__ __launch_bounds__(256) void copy_hc(const float* __restrict__ hT,
                                               const float* __restrict__ cT,
                                               float* __restrict__ out) {
    int i = blockIdx.x * 256 + threadIdx.x;  // 0..65535
    int b = i >> 10, j = i & 1023;
    out[i] = hT[j * 64 + b];
    out[65536 + i] = cT[j * 64 + b];
}

extern "C" void kernel_launch(void* const* d_in, const int* in_sizes, int n_in,
                              void* d_out, int out_size, void* d_ws, size_t ws_size,
                              hipStream_t stream) {
    const float* h0 = (const float*)d_in[1];
    const float* c0 = (const float*)d_in[2];
    const int* tgt = (const int*)d_in[3];
    const float* emb = (const float*)d_in[4];
    const float* Wih = (const float*)d_in[5];
    const float* Whh = (const float*)d_in[6];
    const float* bih = (const float*)d_in[7];
    const float* bhh = (const float*)d_in[8];
    const float* Wout = (const float*)d_in[9];
    const float* bout = (const float*)d_in[10];
    float* out = (float*)d_out;

    char* ws = (char*)d_ws;
    size_t o = 0;
    auto al = [&](size_t bytes) { size_t r = o; o += (bytes + 255) & ~255UL; return r; };
    u16* wih_bf = (u16*)(ws + al(4096ul * 1024 * 2));
    u16* wout_bf = (u16*)(ws + al(32000ul * 1024 * 2));
    u16* x_bf = (u16*)(ws + al(3840ul * 1024 * 2));
    u16* hs_bf = (u16*)(ws + al(3840ul * 1024 * 2));
    float* xWT = (float*)(ws + al(60ul * 4096 * 64 * 4));
    float* wpack = (float*)(ws + al(4096ul * 1024 * 4));
    float* hbuf = (float*)(ws + al(2ul * 65536 * 4));  // ping-pong h
    float* cT = (float*)(ws + al(65536ul * 4));

    cvt_bf16_k<<<(4096 * 1024 / 4 + 255) / 256, 256, 0, stream>>>(Wih, wih_bf, 4096 * 1024 / 4);
    cvt_bf16_k<<<(32000 * 1024 / 4 + 255) / 256, 256, 0, stream>>>(Wout, wout_bf, 32000 * 1024 / 4);
    pack_whh<<<dim3(512, 4), 256, 0, stream>>>(Whh, wpack);
    embed_relu<<<dim3(60, 64), 256, 0, stream>>>(tgt, emb, x_bf);
    init_hc<<<256, 256, 0, stream>>>(h0, c0, hbuf, cT);
    // xW[t,b,n] = relu(emb) @ W_ih^T + (b_ih + b_hh), stored transposed [t][n][b]
    gemm_bt<0, 32><<<dim3(32, 30), 256, 0, stream>>>(x_bf, wih_bf, bih, bhh, xWT);
    for (int t = 0; t < 60; ++t) {
        const float* hR = hbuf + (t & 1) * 65536;
        float* hW = hbuf + ((t + 1) & 1) * 65536;
        lstm_step<<<512, 128, 0, stream>>>(xWT, wpack, hR, hW, cT, hs_bf, t);
    }
    // logits[b][t][v] = hs @ W_out^T + b_out
    gemm_bt<1, 25><<<dim3(250, 30), 256, 0, stream>>>(hs_bf, wout_bf, bout, bout, out);
    softmax_fused<<<3840, 256, 0, stream>>>(out);
    // final h (t=59 writes hbuf[0]) and c
    copy_hc<<<256, 256, 0, stream>>>(hbuf, cT, out + 122880000ul);
}

// Round 2
// 1720.208 us; speedup vs baseline: 1.5657x; 1.4836x over previous
//
#include <hip/hip_runtime.h>

typedef unsigned short u16;
typedef __attribute__((ext_vector_type(8))) short short8;
typedef __attribute__((ext_vector_type(4))) float f32x4;

// ---------- helpers ----------
__device__ __forceinline__ u16 f2bf(float x) {
    unsigned u = __float_as_uint(x);
    u = (u + 0x7FFFu + ((u >> 16) & 1u)) >> 16;
    return (u16)u;
}
__device__ __forceinline__ float bf2f(u16 h) {
    return __uint_as_float((unsigned)h << 16);
}

__device__ __forceinline__ void gload16(const void* g, void* l) {
    __builtin_amdgcn_global_load_lds((const __attribute__((address_space(1))) void*)g,
                                     (__attribute__((address_space(3))) void*)l, 16, 0, 0);
}

// ---------- fp32 -> bf16 convert ----------
__global__ __launch_bounds__(256) void cvt_bf16_k(const float* __restrict__ in,
                                                  u16* __restrict__ out, int n4) {
    int i = blockIdx.x * 256 + threadIdx.x;
    if (i >= n4) return;
    float4 v = ((const float4*)in)[i];
    ushort4 o;
    o.x = f2bf(v.x); o.y = f2bf(v.y); o.z = f2bf(v.z); o.w = f2bf(v.w);
    ((ushort4*)out)[i] = o;
}

// ---------- Whh -> per-block MFMA B-fragment stream, split hi/lo bf16 ----------
// Block p of lstm_step owns 16 gate cols: local g -> n = (g>>2)*1024 + 4p + (g&3).
// Panel layout (u16): wpk[p][chunk c:8][kstep ds:4][part pi:2][frag 512]
//   frag: lane l holds B[n = l&15][k = c*128 + ds*32 + (l>>4)*8 + e], e=0..7
//   at u16 offset l*8 + e.
__global__ __launch_bounds__(256) void pack_whh(const float* __restrict__ Whh,
                                                u16* __restrict__ wpk) {
    const int p = blockIdx.x;   // 0..255
    const int c = blockIdx.y;   // 0..7
    u16* dst = wpk + ((size_t)p * 8 + c) * 4096;  // 8KB chunk
#pragma unroll
    for (int i = 0; i < 8; ++i) {
        int e = i * 256 + threadIdx.x;  // 0..2047
        int g = e >> 7, kk = e & 127;
        int n = (g >> 2) * 1024 + p * 4 + (g & 3);
        float wv = Whh[(size_t)n * 1024 + c * 128 + kk];
        u16 hi = f2bf(wv);
        u16 lo = f2bf(wv - bf2f(hi));
        int ds = kk >> 5;
        int l = g + 16 * ((kk >> 3) & 3);
        int off = (ds * 2) * 512 + l * 8 + (kk & 7);
        dst[off] = hi;
        dst[off + 512] = lo;
    }
}

// ---------- embedding + relu -> bf16 A-matrix rows m = t*64+b ----------
__global__ __launch_bounds__(256) void embed_relu(const int* __restrict__ tgt,
                                                  const float* __restrict__ emb,
                                                  u16* __restrict__ x_bf) {
    int t = blockIdx.x, b = blockIdx.y;
    int tok = (t == 0) ? 0 : tgt[b * 60 + t - 1];
    const float4* src = (const float4*)(emb + (size_t)tok * 1024);
    ushort4* dst = (ushort4*)(x_bf + (size_t)(t * 64 + b) * 1024);
    float4 v = src[threadIdx.x];
    ushort4 o;
    o.x = f2bf(fmaxf(v.x, 0.f)); o.y = f2bf(fmaxf(v.y, 0.f));
    o.z = f2bf(fmaxf(v.z, 0.f)); o.w = f2bf(fmaxf(v.w, 0.f));
    dst[threadIdx.x] = o;
}

// ---------- h0 -> A-frag stream (hi/lo), c0 -> cT [j][b] ----------
// hA layout (u16): [kstep s:32][mfrag m:4][part pi:2][frag 512]
//   frag: lane l holds A[b = 16m + (l&15)][k = 32s + (l>>4)*8 + e] at l*8+e.
__global__ __launch_bounds__(256) void init_pack(const float* __restrict__ h0,
                                                 const float* __restrict__ c0,
                                                 u16* __restrict__ hA0,
                                                 float* __restrict__ cT) {
    int i = blockIdx.x * 256 + threadIdx.x;  // 65536, j fast
    int b = i >> 10, j = i & 1023;
    float v = h0[i];
    cT[j * 64 + b] = c0[i];
    u16 hi = f2bf(v);
    u16 lo = f2bf(v - bf2f(hi));
    int s = j >> 5, m = b >> 4;
    int l = (b & 15) + 16 * ((j >> 3) & 3);
    size_t off = (size_t)((s * 4 + m) * 2) * 512 + l * 8 + (j & 7);
    hA0[off] = hi;
    hA0[off + 512] = lo;
}

// ---------- bf16 MFMA GEMM, A[M,K] @ B^T[N,K], K=1024, 128x128 tiles ----------
// EPI=0: out = xWT[t][n][b] (+b_ih+b_hh);  EPI=1: out = logits[b][t][v] (+b_out)
// GW: supertile width in N-tiles (group = GW x 30 blocks) for L3 locality.
template <int EPI, int GW>
__global__ __launch_bounds__(256) void gemm_bt(const u16* __restrict__ A,
                                               const u16* __restrict__ Bm,
                                               const float* __restrict__ bias0,
                                               const float* __restrict__ bias1,
                                               float* __restrict__ out) {
    constexpr int K = 1024;
    __shared__ u16 lds_a[128 * 32];
    __shared__ u16 lds_b[128 * 32];
    const int tid = threadIdx.x;
    const int lane = tid & 63, wave = tid >> 6;
    const int lin = blockIdx.y * gridDim.x + blockIdx.x;
    constexpr int GSZ = GW * 30;
    const int grp = lin / GSZ, rr = lin % GSZ;
    const int tileN = (grp * GW + rr % GW) * 128;
    const int tileM = (rr / GW) * 128;
    const int wm = (wave >> 1) * 64, wn = (wave & 1) * 64;

    const int sRow = wave * 32 + (lane >> 2);
    const int sCol = (lane & 3) * 8;
    const u16* gA = A + (size_t)(tileM + sRow) * K + sCol;
    const u16* gB = Bm + (size_t)(tileN + sRow) * K + sCol;
    u16* lA = lds_a + sRow * 32 + sCol;
    u16* lB = lds_b + sRow * 32 + sCol;

    f32x4 acc[4][4] = {};
    const int fr = lane & 15, fq = lane >> 4;

    for (int k0 = 0; k0 < K; k0 += 32) {
        gload16(gA + k0, lA);
        gload16(gA + k0 + 16 * K, lA + 16 * 32);
        gload16(gB + k0, lB);
        gload16(gB + k0 + 16 * K, lB + 16 * 32);
        __syncthreads();
        short8 af[4], bfv[4];
#pragma unroll
        for (int i = 0; i < 4; ++i)
            af[i] = *(const short8*)&lds_a[(wm + i * 16 + fr) * 32 + fq * 8];
#pragma unroll
        for (int j = 0; j < 4; ++j)
            bfv[j] = *(const short8*)&lds_b[(wn + j * 16 + fr) * 32 + fq * 8];
#pragma unroll
        for (int i = 0; i < 4; ++i)
#pragma unroll
            for (int j = 0; j < 4; ++j)
                acc[i][j] = __builtin_amdgcn_mfma_f32_16x16x32_bf16(af[i], bfv[j], acc[i][j], 0, 0, 0);
        __syncthreads();
    }
    const int cr = fq * 4, cc = fr;
#pragma unroll
    for (int i = 0; i < 4; ++i) {
#pragma unroll
        for (int j = 0; j < 4; ++j) {
            int col = tileN + wn + j * 16 + cc;
            float bb;
            if (EPI == 0) bb = bias0[col] + bias1[col];
            else          bb = bias0[col];
#pragma unroll
            for (int r = 0; r < 4; ++r) {
                int row = tileM + wm + i * 16 + cr + r;  // row = t*64 + b
                float v = acc[i][j][r] + bb;
                if (EPI == 0) {
                    out[((size_t)(row >> 6) * 4096 + col) * 64 + (row & 63)] = v;
                } else {
                    out[((size_t)(row & 63) * 60 + (row >> 6)) * 32000 + col] = v;
                }
            }
        }
    }
}

// ---------- fused recurrent step: MFMA gates GEMM (split-bf16) + LSTM update ----------
// 256 blocks x 256 thr (4 waves). Block p: gate cols n = q*1024 + 4p + jj (g=q*4+jj).
// gates = hHi@WHi + hHi@WLo + hLo@WHi  (error ~2^-17, f32-equivalent).
// Wave w computes m-frag w (b in [16w,16w+16)), single n-frag.
// K=1024 in 8 chunks of 128; A-chunk 32KB + W-chunk 8KB, double-buffered.
__global__ __launch_bounds__(256) void lstm_step(const float* __restrict__ xWT,
                                                 const u16* __restrict__ wpk,
                                                 const u16* __restrict__ hA,
                                                 u16* __restrict__ hAn,
                                                 float* __restrict__ cT,
                                                 float* __restrict__ hT,
                                                 u16* __restrict__ hs_bf, int t) {
    __shared__ __attribute__((aligned(16))) u16 buf[2][20480];  // 2 x 40KB
    const int tid = threadIdx.x;
    const int p = blockIdx.x;
    const int lane = tid & 63, wv = tid >> 6;

    // update-role indices; prefetch xW gates + c_old early (HBM latency)
    const int eb = tid & 63, ejj = tid >> 6;
    const int j = p * 4 + ejj;
    float xw[4];
    {
        const float* xb = xWT + (size_t)t * 262144 + (size_t)j * 64 + eb;
#pragma unroll
        for (int q = 0; q < 4; ++q) xw[q] = xb[(size_t)q * 65536];
    }
    float cold = cT[j * 64 + eb];

    const u16* gW = wpk + (size_t)p * 32768;  // 64KB panel (u16 units)
    // STAGE chunk c into buf[bsel]: A 32KB (hA + c*16384) then W 8KB (gW + c*4096)
#define STAGE(c, bsel)                                                             \
    {                                                                              \
        u16* d = buf[bsel];                                                        \
        const u16* sa = hA + (size_t)(c) * 16384;                                  \
        _Pragma("unroll") for (int i_ = 0; i_ < 8; ++i_)                           \
            gload16(sa + i_ * 2048 + tid * 8, d + i_ * 2048 + tid * 8);            \
        const u16* sw = gW + (size_t)(c) * 4096;                                   \
        _Pragma("unroll") for (int i_ = 0; i_ < 2; ++i_)                           \
            gload16(sw + i_ * 2048 + tid * 8, d + 16384 + i_ * 2048 + tid * 8);    \
    }

    STAGE(0, 0);
    __syncthreads();  // vmcnt(0) drain: chunk 0 resident

    f32x4 acc = {};
    for (int c = 0; c < 8; ++c) {
        if (c < 7) STAGE(c + 1, (c + 1) & 1);  // issue next-chunk loads first
        const u16* A = buf[c & 1];
        const u16* W = buf[c & 1] + 16384;
#pragma unroll
        for (int ds = 0; ds < 4; ++ds) {
            short8 ah = *(const short8*)(A + ((ds * 4 + wv) * 2 + 0) * 512 + lane * 8);
            short8 al = *(const short8*)(A + ((ds * 4 + wv) * 2 + 1) * 512 + lane * 8);
            short8 bh = *(const short8*)(W + (ds * 2 + 0) * 512 + lane * 8);
            short8 bl = *(const short8*)(W + (ds * 2 + 1) * 512 + lane * 8);
            acc = __builtin_amdgcn_mfma_f32_16x16x32_bf16(ah, bh, acc, 0, 0, 0);
            acc = __builtin_amdgcn_mfma_f32_16x16x32_bf16(ah, bl, acc, 0, 0, 0);
            acc = __builtin_amdgcn_mfma_f32_16x16x32_bf16(al, bh, acc, 0, 0, 0);
        }
        __syncthreads();  // loads for c+1 done; buf[c&1] free for c+2
    }
#undef STAGE

    // gather gates: lane holds col g = lane&15, rows b = 16*wv + (lane>>4)*4 + r
    float* gbuf = (float*)buf;  // 4KB, all LDS reads done
    {
        int g = lane & 15, br = wv * 16 + (lane >> 4) * 4;
#pragma unroll
        for (int r = 0; r < 4; ++r) gbuf[g * 64 + br + r] = acc[r];
    }
    __syncthreads();
    float gq[4];
#pragma unroll
    for (int q = 0; q < 4; ++q) gq[q] = gbuf[(q * 4 + ejj) * 64 + eb] + xw[q];
    float ig = 1.f / (1.f + __expf(-gq[0]));
    float fg = 1.f / (1.f + __expf(-gq[1]));
    float gg = tanhf(gq[2]);
    float og = 1.f / (1.f + __expf(-gq[3]));
    float cn = fg * cold + ig * gg;
    float hn = og * tanhf(cn);
    cT[j * 64 + eb] = cn;
    hT[j * 64 + eb] = hn;
    hs_bf[(size_t)(t * 64 + eb) * 1024 + j] = f2bf(hn);
    // write next-step A-frags (hi/lo split)
    u16 hi = f2bf(hn);
    u16 lo = f2bf(hn - bf2f(hi));
    int s = j >> 5, m = eb >> 4;
    int l = (eb & 15) + 16 * ((j >> 3) & 3);
    size_t off = (size_t)((s * 4 + m) * 2) * 512 + l * 8 + (j & 7);
    hAn[off] = hi;
    hAn[off + 512] = lo;
}

// ---------- fused log_softmax: row in registers, one read + one write ----------
__global__ __launch_bounds__(256) void softmax_fused(float* __restrict__ logits) {
    const int tid = threadIdx.x;
    float* x = logits + (size_t)blockIdx.x * 32000;
    float4* x4 = (float4*)x;
    float4 v[31];
#pragma unroll
    for (int i = 0; i < 31; ++i) v[i] = x4[i * 256 + tid];
    float vt = x[31744 + tid];
    float m = vt;
#pragma unroll
    for (int i = 0; i < 31; ++i)
        m = fmaxf(m, fmaxf(fmaxf(v[i].x, v[i].y), fmaxf(v[i].z, v[i].w)));
#pragma unroll
    for (int o = 32; o > 0; o >>= 1) m = fmaxf(m, __shfl_xor(m, o));
    __shared__ float red[8];
    const int lane = tid & 63, wv = tid >> 6;
    if (lane == 0) red[wv] = m;
    __syncthreads();
    m = fmaxf(fmaxf(red[0], red[1]), fmaxf(red[2], red[3]));
    float s = __expf(vt - m);
#pragma unroll
    for (int i = 0; i < 31; ++i)
        s += __expf(v[i].x - m) + __expf(v[i].y - m) + __expf(v[i].z - m) + __expf(v[i].w - m);
#pragma unroll
    for (int o = 32; o > 0; o >>= 1) s += __shfl_xor(s, o);
    if (lane == 0) red[4 + wv] = s;
    __syncthreads();
    float d = m + __logf(red[4] + red[5] + red[6] + red[7]);
#pragma unroll
    for (int i = 0; i < 31; ++i) {
        v[i].x -= d; v[i].y -= d; v[i].z -= d; v[i].w -= d;
        x4[i * 256 + tid] = v[i];
    }
    x[31744 + tid] = vt - d;
}

// ---------- final h,c -> d_out tail ----------
__global__ __launch_bounds__(256) void copy_hc(const float* __restrict__ hT,
                                               const float* __restrict__ cT,
                                               float* __restrict__ out) {
    int i = blockIdx.x * 256 + threadIdx.x;  // 0..65535
    int b = i >> 10, j = i & 1023;
    out[i] = hT[j * 64 + b];
    out[65536 + i] = cT[j * 64 + b];
}

extern "C" void kernel_launch(void* const* d_in, const int* in_sizes, int n_in,
                              void* d_out, int out_size, void* d_ws, size_t ws_size,
                              hipStream_t stream) {
    const float* h0 = (const float*)d_in[1];
    const float* c0 = (const float*)d_in[2];
    const int* tgt = (const int*)d_in[3];
    const float* emb = (const float*)d_in[4];
    const float* Wih = (const float*)d_in[5];
    const float* Whh = (const float*)d_in[6];
    const float* bih = (const float*)d_in[7];
    const float* bhh = (const float*)d_in[8];
    const float* Wout = (const float*)d_in[9];
    const float* bout = (const float*)d_in[10];
    float* out = (float*)d_out;

    char* ws = (char*)d_ws;
    size_t o = 0;
    auto al = [&](size_t bytes) { size_t r = o; o += (bytes + 255) & ~255UL; return r; };
    u16* wih_bf = (u16*)(ws + al(4096ul * 1024 * 2));
    u16* wout_bf = (u16*)(ws + al(32000ul * 1024 * 2));
    u16* x_bf = (u16*)(ws + al(3840ul * 1024 * 2));
    u16* hs_bf = (u16*)(ws + al(3840ul * 1024 * 2));
    float* xWT = (float*)(ws + al(60ul * 4096 * 64 * 4));
    u16* wpk = (u16*)(ws + al(256ul * 32768 * 2));    // 16MB W frag panels
    u16* hApp = (u16*)(ws + al(2ul * 131072 * 2));    // ping-pong h frag streams
    float* cT = (float*)(ws + al(65536ul * 4));
    float* hT = (float*)(ws + al(65536ul * 4));

    cvt_bf16_k<<<(4096 * 1024 / 4 + 255) / 256, 256, 0, stream>>>(Wih, wih_bf, 4096 * 1024 / 4);
    cvt_bf16_k<<<(32000 * 1024 / 4 + 255) / 256, 256, 0, stream>>>(Wout, wout_bf, 32000 * 1024 / 4);
    pack_whh<<<dim3(256, 8), 256, 0, stream>>>(Whh, wpk);
    embed_relu<<<dim3(60, 64), 256, 0, stream>>>(tgt, emb, x_bf);
    init_pack<<<256, 256, 0, stream>>>(h0, c0, hApp, cT);
    // xW[t,b,n] = relu(emb) @ W_ih^T + (b_ih + b_hh), stored transposed [t][n][b]
    gemm_bt<0, 32><<<dim3(32, 30), 256, 0, stream>>>(x_bf, wih_bf, bih, bhh, xWT);
    for (int t = 0; t < 60; ++t) {
        const u16* hR = hApp + (size_t)(t & 1) * 131072;
        u16* hW = hApp + (size_t)((t + 1) & 1) * 131072;
        lstm_step<<<256, 256, 0, stream>>>(xWT, wpk, hR, hW, cT, hT, hs_bf, t);
    }
    // logits[b][t][v] = hs @ W_out^T + b_out
    gemm_bt<1, 25><<<dim3(250, 30), 256, 0, stream>>>(hs_bf, wout_bf, bout, bout, out);
    softmax_fused<<<3840, 256, 0, stream>>>(out);
    copy_hc<<<256, 256, 0, stream>>>(hT, cT, out + 122880000ul);
}